// Round 4
// baseline (2412.350 us; speedup 1.0000x reference)
//
#include <hip/hip_runtime.h>

#define B 4096
#define T 2048
#define H 64
#define NBATCH 16
#define NB (B / NBATCH)     // 256 blocks -> 1 per CU
#define NTHREADS 512        // 8 waves -> 2 waves/SIMD

typedef __attribute__((ext_vector_type(8))) short short8;
typedef __attribute__((ext_vector_type(4))) float f32x4;

__device__ __forceinline__ float ex2(float x) { return __builtin_amdgcn_exp2f(x); }
__device__ __forceinline__ float sigm(float x) {
    return __builtin_amdgcn_rcpf(1.0f + ex2(-1.4426950408889634f * x));
}
// tanh(x) = 2*sigmoid(2x)-1 : 5 ops, saturates correctly at +-inf.
__device__ __forceinline__ float tanh_(float x) {
    return __builtin_fmaf(2.0f,
        __builtin_amdgcn_rcpf(1.0f + ex2(-2.8853900817779268f * x)), -1.0f);
}
__device__ __forceinline__ unsigned short f2bf(float f) {  // RNE f32->bf16
    unsigned u = __builtin_bit_cast(unsigned, f);
    u += 0x7fffu + ((u >> 16) & 1u);
    return (unsigned short)(u >> 16);
}
// LDS-only barrier: drain lgkm (ds ops) but leave global loads in flight.
__device__ __forceinline__ void lds_barrier() {
    asm volatile("s_waitcnt lgkmcnt(0)\n\ts_barrier" ::: "memory");
}

// ---------------------------------------------------------------------------
// Split-batch ping-pong LSTM: block = 16 batches as TWO independent 8-batch
// sub-problems S0 (batches b0..b0+7), S1 (b0+8..b0+15). Each inter-barrier
// region does: activations for S_q (gates in regs from previous region,
// latency-free to start) overlapped with ds_read+MFMA for S_p. Gates hand
// off in registers; hX needs no double buffer (region reads hX[p], writes
// hX[q], p!=q, barriers separate rounds).
// MFMA cols = 8 batches x 2 replicas; lane (c,hi) activates the quad of
// tile rt = c>>3: cell (batch cb=c&7, unit u = w*8 + (c>>3)*4 + hi)
// [mapping verified in earlier rounds].
// hX row stride 80 shorts: bank-spread for the b128 fragment reads.
// ---------------------------------------------------------------------------
extern "C" __global__ void __launch_bounds__(NTHREADS, 2)
enc_kernel(const float* __restrict__ padded, const int* __restrict__ seq_len,
           const float* __restrict__ Wih, const float* __restrict__ Whh,
           const float* __restrict__ bias,
           float* __restrict__ h_out, float* __restrict__ c_out)
{
    __shared__ unsigned short hX[2][8][80];
    __shared__ int slen[NBATCH];

    const int tid = threadIdx.x;
    const int w = tid >> 6, L = tid & 63, c = L & 15, hi = L >> 4;
    const int b0 = blockIdx.x * NBATCH;
    const int cb = c & 7;
    const int rsel = c >> 3;                  // which rt-quad this lane activates
    const int u = w * 8 + rsel * 4 + hi;      // lane's unit (both problems)

    // A-frags, remapped rows G(m,rt) = (m&3)*64 + w*8+rt*4 + (m>>2)
    short8 af[2][2];
    #pragma unroll
    for (int rt = 0; rt < 2; ++rt) {
        const int G = (c & 3) * 64 + w * 8 + rt * 4 + (c >> 2);
        #pragma unroll
        for (int kk = 0; kk < 2; ++kk) {
            const float* src = Whh + (long)G * H + kk * 32 + hi * 8;
            short8 f;
            #pragma unroll
            for (int j = 0; j < 8; ++j) f[j] = (short)f2bf(src[j]);
            af[rt][kk] = f;
        }
    }
    // z-init coefs: C row hi*4+r of tile rt = gate r of unit w*8+rt*4+hi
    float b_g[2][4], wi_g[2][4];
    #pragma unroll
    for (int rt = 0; rt < 2; ++rt)
        #pragma unroll
        for (int r = 0; r < 4; ++r) {
            const int G2 = r * 64 + w * 8 + rt * 4 + hi;
            b_g[rt][r] = bias[G2];
            wi_g[rt][r] = Wih[G2];
        }

    for (int idx = tid; idx < 2 * 8 * 80; idx += NTHREADS)
        ((unsigned short*)hX)[idx] = 0;
    if (tid < NBATCH) slen[tid] = seq_len[b0 + tid];
    lds_barrier();

    int maxlen = 1;
    #pragma unroll
    for (int i = 0; i < NBATCH; ++i) maxlen = max(maxlen, slen[i]);
    const int len0 = slen[cb];
    const int len1 = slen[8 + cb];

    const float* xrow0 = padded + (long)(b0 + cb) * T;
    const float* xrow1 = padded + (long)(b0 + 8 + cb) * T;
    f32x4 xc0 = *(const f32x4*)(xrow0), xn0 = *(const f32x4*)(xrow0 + 4);
    f32x4 xc1 = *(const f32x4*)(xrow1), xn1 = *(const f32x4*)(xrow1 + 4);

    float cs0 = 0.f, hs0 = 0.f, cs1 = 0.f, hs1 = 0.f;
    // gate regs; gz1* zero-init => the m=0 fake act(S1,-1) yields c=h=0 exactly
    f32x4 gz00 = {0.f,0.f,0.f,0.f}, gz01 = {0.f,0.f,0.f,0.f};
    f32x4 gz10 = {0.f,0.f,0.f,0.f}, gz11 = {0.f,0.f,0.f,0.f};

// even region at step t+I: act(S1, t+I-1) + MFMA(S0, t+I)
#define REV(I)                                                                \
    {                                                                         \
        short8 hb0 = *(const short8*)&hX[0][cb][hi * 8];                      \
        short8 hb1 = *(const short8*)&hX[0][cb][32 + hi * 8];                 \
        {                                                                     \
            float a0 = rsel ? gz11[0] : gz10[0];                              \
            float a1 = rsel ? gz11[1] : gz10[1];                              \
            float a2 = rsel ? gz11[2] : gz10[2];                              \
            float a3 = rsel ? gz11[3] : gz10[3];                              \
            float i_ = sigm(a0), f_ = sigm(a1);                               \
            float g_ = tanh_(a2), o_ = sigm(a3);                              \
            float cn = f_ * cs1 + i_ * g_;                                    \
            float hn = o_ * tanh_(cn);                                        \
            if ((t + (I) - 1) < len1) { cs1 = cn; hs1 = hn; }                 \
            hX[1][cb][u] = f2bf(hs1);                                         \
        }                                                                     \
        const float x = xc0[I];                                               \
        f32x4 z0 = {b_g[0][0] + wi_g[0][0] * x, b_g[0][1] + wi_g[0][1] * x,   \
                    b_g[0][2] + wi_g[0][2] * x, b_g[0][3] + wi_g[0][3] * x};  \
        f32x4 z1 = {b_g[1][0] + wi_g[1][0] * x, b_g[1][1] + wi_g[1][1] * x,   \
                    b_g[1][2] + wi_g[1][2] * x, b_g[1][3] + wi_g[1][3] * x};  \
        z0 = __builtin_amdgcn_mfma_f32_16x16x32_bf16(af[0][0], hb0, z0, 0,0,0); \
        z1 = __builtin_amdgcn_mfma_f32_16x16x32_bf16(af[1][0], hb0, z1, 0,0,0); \
        z0 = __builtin_amdgcn_mfma_f32_16x16x32_bf16(af[0][1], hb1, z0, 0,0,0); \
        z1 = __builtin_amdgcn_mfma_f32_16x16x32_bf16(af[1][1], hb1, z1, 0,0,0); \
        gz00 = z0; gz01 = z1;                                                 \
        lds_barrier();                                                        \
    }

// odd region at step t+I: act(S0, t+I) + MFMA(S1, t+I)
#define ROD(I)                                                                \
    {                                                                         \
        short8 hb0 = *(const short8*)&hX[1][cb][hi * 8];                      \
        short8 hb1 = *(const short8*)&hX[1][cb][32 + hi * 8];                 \
        {                                                                     \
            float a0 = rsel ? gz01[0] : gz00[0];                              \
            float a1 = rsel ? gz01[1] : gz00[1];                              \
            float a2 = rsel ? gz01[2] : gz00[2];                              \
            float a3 = rsel ? gz01[3] : gz00[3];                              \
            float i_ = sigm(a0), f_ = sigm(a1);                               \
            float g_ = tanh_(a2), o_ = sigm(a3);                              \
            float cn = f_ * cs0 + i_ * g_;                                    \
            float hn = o_ * tanh_(cn);                                        \
            if ((t + (I)) < len0) { cs0 = cn; hs0 = hn; }                     \
            hX[0][cb][u] = f2bf(hs0);                                         \
        }                                                                     \
        const float x = xc1[I];                                               \
        f32x4 z0 = {b_g[0][0] + wi_g[0][0] * x, b_g[0][1] + wi_g[0][1] * x,   \
                    b_g[0][2] + wi_g[0][2] * x, b_g[0][3] + wi_g[0][3] * x};  \
        f32x4 z1 = {b_g[1][0] + wi_g[1][0] * x, b_g[1][1] + wi_g[1][1] * x,   \
                    b_g[1][2] + wi_g[1][2] * x, b_g[1][3] + wi_g[1][3] * x};  \
        z0 = __builtin_amdgcn_mfma_f32_16x16x32_bf16(af[0][0], hb0, z0, 0,0,0); \
        z1 = __builtin_amdgcn_mfma_f32_16x16x32_bf16(af[1][0], hb0, z1, 0,0,0); \
        z0 = __builtin_amdgcn_mfma_f32_16x16x32_bf16(af[0][1], hb1, z0, 0,0,0); \
        z1 = __builtin_amdgcn_mfma_f32_16x16x32_bf16(af[1][1], hb1, z1, 0,0,0); \
        gz10 = z0; gz11 = z1;                                                 \
        lds_barrier();                                                        \
    }

    int t = 0;
    for (; t < maxlen; t += 4) {
        int nb = t + 8; if (nb > T - 4) nb = T - 4;
        f32x4 xf0 = *(const f32x4*)(xrow0 + nb);
        f32x4 xf1 = *(const f32x4*)(xrow1 + nb);
        REV(0) ROD(0) REV(1) ROD(1) REV(2) ROD(2) REV(3) ROD(3)
        xc0 = xn0; xn0 = xf0;
        xc1 = xn1; xn1 = xf1;
    }
#undef REV
#undef ROD
    {   // pending act(S1, t-1): registers only, no LDS write needed
        float a0 = rsel ? gz11[0] : gz10[0];
        float a1 = rsel ? gz11[1] : gz10[1];
        float a2 = rsel ? gz11[2] : gz10[2];
        float a3 = rsel ? gz11[3] : gz10[3];
        float i_ = sigm(a0), f_ = sigm(a1);
        float g_ = tanh_(a2), o_ = sigm(a3);
        float cn = f_ * cs1 + i_ * g_;
        float hn = o_ * tanh_(cn);
        if ((t - 1) < len1) { cs1 = cn; hs1 = hn; }
    }

    h_out[(long)(b0 + cb) * H + u] = hs0;
    c_out[(long)(b0 + cb) * H + u] = cs0;
    h_out[(long)(b0 + 8 + cb) * H + u] = hs1;
    c_out[(long)(b0 + 8 + cb) * H + u] = cs1;
}

// ---------------------------------------------------------------------------
// Bottleneck + y0 correction term for the decoder's rank-1 fold.
// ---------------------------------------------------------------------------
extern "C" __global__ void __launch_bounds__(256)
mid_kernel(const float* __restrict__ h_enc,
           const float* __restrict__ eW, const float* __restrict__ eb,
           const float* __restrict__ dW, const float* __restrict__ db,
           const float* __restrict__ outW, const float* __restrict__ outb,
           float* __restrict__ hz_out, float* __restrict__ hd_out,
           float* __restrict__ y0c)
{
    int b = blockIdx.x * blockDim.x + threadIdx.x;
    if (b >= B) return;
    const float* h = h_enc + (long)b * H;
    float hz[3];
    #pragma unroll
    for (int j = 0; j < 3; ++j) {
        float s = eb[j];
        for (int k = 0; k < H; ++k) s += h[k] * eW[j*H + k];
        hz[j] = sigm(s);
        hz_out[b*3 + j] = hz[j];
    }
    float y0 = outb[0];
    for (int u = 0; u < H; ++u) {
        float hd = db[u] + hz[0]*dW[u*3] + hz[1]*dW[u*3+1] + hz[2]*dW[u*3+2];
        hd_out[(long)b*H + u] = hd;
        y0 += outW[u] * hd;
    }
    y0c[b] = y0;
}

// ---------------------------------------------------------------------------
// Decoder: rank-1 fold (W' = Whh + Wih (x) outW, b' = b + Wih*outb) -> pure
// LSTM, same split-batch ping-pong. y_{t} extracted in the MFMA region that
// reads h_t (rotating wave w == step&7). t=0 correction peeled (first two
// regions); final S1 y in an epilogue read.
// ---------------------------------------------------------------------------
extern "C" __global__ void __launch_bounds__(NTHREADS, 2)
dec_kernel(const float* __restrict__ hd, const float* __restrict__ c_in,
           const float* __restrict__ Wih, const float* __restrict__ Whh,
           const float* __restrict__ bias, const float* __restrict__ outW,
           const float* __restrict__ outb, const float* __restrict__ y0c,
           float* __restrict__ y_out)
{
    __shared__ unsigned short hX[2][8][80];

    const int tid = threadIdx.x;
    const int w = tid >> 6, L = tid & 63, c = L & 15, hi = L >> 4;
    const int b0 = blockIdx.x * NBATCH;
    const int cb = c & 7;
    const int rsel = c >> 3;
    const int u = w * 8 + rsel * 4 + hi;

    short8 af[2][2];
    #pragma unroll
    for (int rt = 0; rt < 2; ++rt) {
        const int G = (c & 3) * 64 + w * 8 + rt * 4 + (c >> 2);
        const float wir = Wih[G];
        #pragma unroll
        for (int kk = 0; kk < 2; ++kk) {
            const float* src = Whh + (long)G * H + kk * 32 + hi * 8;
            const float* ow  = outW + kk * 32 + hi * 8;
            short8 f;
            #pragma unroll
            for (int j = 0; j < 8; ++j) f[j] = (short)f2bf(src[j] + wir * ow[j]);
            af[rt][kk] = f;
        }
    }
    const float outb_s = outb[0];
    const float y00 = y0c[b0 + cb];
    const float y01 = y0c[b0 + 8 + cb];
    float zb[2][4], wih_a[4];
    #pragma unroll
    for (int rt = 0; rt < 2; ++rt)
        #pragma unroll
        for (int r = 0; r < 4; ++r) {
            const int G2 = r * 64 + w * 8 + rt * 4 + hi;
            zb[rt][r] = bias[G2] + Wih[G2] * outb_s;
        }
    #pragma unroll
    for (int r = 0; r < 4; ++r) wih_a[r] = Wih[r * 64 + u];

    short8 ya[2];   // y-extraction A-frag: row 0 = outW, rows 1..15 = 0
    #pragma unroll
    for (int kk = 0; kk < 2; ++kk) {
        short8 f = (short8)0;
        if (c == 0)
            #pragma unroll
            for (int j = 0; j < 8; ++j) f[j] = (short)f2bf(outW[kk*32 + hi*8 + j]);
        ya[kk] = f;
    }

    for (int idx = tid; idx < 1024; idx += NTHREADS) {
        int p = idx >> 9, m = (idx >> 6) & 7, k = idx & 63;
        hX[p][m][k] = f2bf(hd[(long)(b0 + 8 * p + m) * H + k]);
    }
    float cs0 = c_in[(long)(b0 + cb) * H + u];
    float cs1 = c_in[(long)(b0 + 8 + cb) * H + u];
    f32x4 gz00, gz01, gz10, gz11;
    lds_barrier();

    {   // pre-region: MFMA(S0, 0) from hd; no y (t-1 < 0)
        short8 hb0 = *(const short8*)&hX[0][cb][hi * 8];
        short8 hb1 = *(const short8*)&hX[0][cb][32 + hi * 8];
        f32x4 z0 = {zb[0][0], zb[0][1], zb[0][2], zb[0][3]};
        f32x4 z1 = {zb[1][0], zb[1][1], zb[1][2], zb[1][3]};
        z0 = __builtin_amdgcn_mfma_f32_16x16x32_bf16(af[0][0], hb0, z0, 0,0,0);
        z1 = __builtin_amdgcn_mfma_f32_16x16x32_bf16(af[1][0], hb0, z1, 0,0,0);
        z0 = __builtin_amdgcn_mfma_f32_16x16x32_bf16(af[0][1], hb1, z0, 0,0,0);
        z1 = __builtin_amdgcn_mfma_f32_16x16x32_bf16(af[1][1], hb1, z1, 0,0,0);
        gz00 = z0; gz01 = z1;
        lds_barrier();
    }

// DRE(TT,CF): act(S0,TT) + MFMA(S1,TT); y(S1,TT-1) when TT>0 (skip if CF)
#define DRE(TT, CF)                                                           \
    {                                                                         \
        short8 hb0 = *(const short8*)&hX[1][cb][hi * 8];                      \
        short8 hb1 = *(const short8*)&hX[1][cb][32 + hi * 8];                 \
        {                                                                     \
            float a0 = rsel ? gz01[0] : gz00[0];                              \
            float a1 = rsel ? gz01[1] : gz00[1];                              \
            float a2 = rsel ? gz01[2] : gz00[2];                              \
            float a3 = rsel ? gz01[3] : gz00[3];                              \
            if (CF) { a0 -= wih_a[0] * y00; a1 -= wih_a[1] * y00;             \
                      a2 -= wih_a[2] * y00; a3 -= wih_a[3] * y00; }           \
            float i_ = sigm(a0), f_ = sigm(a1);                               \
            float g_ = tanh_(a2), o_ = sigm(a3);                              \
            float cn = f_ * cs0 + i_ * g_;                                    \
            float hn = o_ * tanh_(cn);                                        \
            cs0 = cn;                                                         \
            hX[0][cb][u] = f2bf(hn);                                          \
        }                                                                     \
        f32x4 z0 = {zb[0][0], zb[0][1], zb[0][2], zb[0][3]};                  \
        f32x4 z1 = {zb[1][0], zb[1][1], zb[1][2], zb[1][3]};                  \
        z0 = __builtin_amdgcn_mfma_f32_16x16x32_bf16(af[0][0], hb0, z0, 0,0,0); \
        z1 = __builtin_amdgcn_mfma_f32_16x16x32_bf16(af[1][0], hb0, z1, 0,0,0); \
        z0 = __builtin_amdgcn_mfma_f32_16x16x32_bf16(af[0][1], hb1, z0, 0,0,0); \
        z1 = __builtin_amdgcn_mfma_f32_16x16x32_bf16(af[1][1], hb1, z1, 0,0,0); \
        gz10 = z0; gz11 = z1;                                                 \
        if (!(CF) && w == ((TT) & 7)) {                                       \
            f32x4 zy = {outb_s, outb_s, outb_s, outb_s};                      \
            zy = __builtin_amdgcn_mfma_f32_16x16x32_bf16(ya[0], hb0, zy, 0,0,0); \
            zy = __builtin_amdgcn_mfma_f32_16x16x32_bf16(ya[1], hb1, zy, 0,0,0); \
            if (hi == 0 && c < 8)                                             \
                y_out[(long)(b0 + 8 + cb) * T + ((TT) - 1)] = zy[0];          \
        }                                                                     \
        lds_barrier();                                                        \
    }

// DRO(TT,CF): act(S1,TT) + MFMA(S0,TT+1); y(S0,TT) always
#define DRO(TT, CF)                                                           \
    {                                                                         \
        short8 hb0 = *(const short8*)&hX[0][cb][hi * 8];                      \
        short8 hb1 = *(const short8*)&hX[0][cb][32 + hi * 8];                 \
        {                                                                     \
            float a0 = rsel ? gz11[0] : gz10[0];                              \
            float a1 = rsel ? gz11[1] : gz10[1];                              \
            float a2 = rsel ? gz11[2] : gz10[2];                              \
            float a3 = rsel ? gz11[3] : gz10[3];                              \
            if (CF) { a0 -= wih_a[0] * y01; a1 -= wih_a[1] * y01;             \
                      a2 -= wih_a[2] * y01; a3 -= wih_a[3] * y01; }           \
            float i_ = sigm(a0), f_ = sigm(a1);                               \
            float g_ = tanh_(a2), o_ = sigm(a3);                              \
            float cn = f_ * cs1 + i_ * g_;                                    \
            float hn = o_ * tanh_(cn);                                        \
            cs1 = cn;                                                         \
            hX[1][cb][u] = f2bf(hn);                                          \
        }                                                                     \
        f32x4 z0 = {zb[0][0], zb[0][1], zb[0][2], zb[0][3]};                  \
        f32x4 z1 = {zb[1][0], zb[1][1], zb[1][2], zb[1][3]};                  \
        z0 = __builtin_amdgcn_mfma_f32_16x16x32_bf16(af[0][0], hb0, z0, 0,0,0); \
        z1 = __builtin_amdgcn_mfma_f32_16x16x32_bf16(af[1][0], hb0, z1, 0,0,0); \
        z0 = __builtin_amdgcn_mfma_f32_16x16x32_bf16(af[0][1], hb1, z0, 0,0,0); \
        z1 = __builtin_amdgcn_mfma_f32_16x16x32_bf16(af[1][1], hb1, z1, 0,0,0); \
        gz00 = z0; gz01 = z1;                                                 \
        if (w == (((TT) + 1) & 7)) {                                          \
            f32x4 zy = {outb_s, outb_s, outb_s, outb_s};                      \
            zy = __builtin_amdgcn_mfma_f32_16x16x32_bf16(ya[0], hb0, zy, 0,0,0); \
            zy = __builtin_amdgcn_mfma_f32_16x16x32_bf16(ya[1], hb1, zy, 0,0,0); \
            if (hi == 0 && c < 8)                                             \
                y_out[(long)(b0 + cb) * T + (TT)] = zy[0];                    \
        }                                                                     \
        lds_barrier();                                                        \
    }

    DRE(0, 1) DRO(0, 1) DRE(1, 0) DRO(1, 0)
    for (int m = 2; m < T; m += 2) {
        DRE(m, 0) DRO(m, 0) DRE(m + 1, 0) DRO(m + 1, 0)
    }
#undef DRE
#undef DRO

    if (w == 0) {   // final y(S1, T-1); rotation slot (T & 7) == 0
        short8 hb0 = *(const short8*)&hX[1][cb][hi * 8];
        short8 hb1 = *(const short8*)&hX[1][cb][32 + hi * 8];
        f32x4 zy = {outb_s, outb_s, outb_s, outb_s};
        zy = __builtin_amdgcn_mfma_f32_16x16x32_bf16(ya[0], hb0, zy, 0,0,0);
        zy = __builtin_amdgcn_mfma_f32_16x16x32_bf16(ya[1], hb1, zy, 0,0,0);
        if (hi == 0 && c < 8) y_out[(long)(b0 + 8 + cb) * T + (T - 1)] = zy[0];
    }
}

// ---------------------------------------------------------------------------
extern "C" __global__ void __launch_bounds__(256)
loss_kernel(const float* __restrict__ padded, const float* __restrict__ y,
            const int* __restrict__ seq_len, float* __restrict__ acc2)
{
    const long n4 = (long)B * T / 4;
    long i0 = (long)(blockIdx.x * blockDim.x + threadIdx.x);
    long stride = (long)gridDim.x * blockDim.x;
    float s = 0.f, cnt = 0.f;
    for (long i = i0; i < n4; i += stride) {
        int b = (int)(i >> 9);                  // T/4 = 512
        int t = (int)(i & 511) * 4;
        int len = seq_len[b];
        f32x4 pv = *(const f32x4*)&padded[i * 4];
        f32x4 yv = *(const f32x4*)&y[i * 4];
        #pragma unroll
        for (int e = 0; e < 4; ++e)
            if (t + e < len) { float d = pv[e] - yv[e]; s += d * d; cnt += 1.0f; }
    }
    for (int m = 1; m < 64; m <<= 1) { s += __shfl_xor(s, m); cnt += __shfl_xor(cnt, m); }
    if ((threadIdx.x & 63) == 0) { atomicAdd(&acc2[0], s); atomicAdd(&acc2[1], cnt); }
}

extern "C" __global__ void fin_kernel(const float* __restrict__ acc2, float* __restrict__ out)
{
    out[0] = acc2[0] / acc2[1];
}

// ---------------------------------------------------------------------------
extern "C" void kernel_launch(void* const* d_in, const int* in_sizes, int n_in,
                              void* d_out, int out_size, void* d_ws, size_t ws_size,
                              hipStream_t stream)
{
    const float* padded = (const float*)d_in[0];
    const int*   seq    = (const int*)  d_in[1];
    const float* eWih   = (const float*)d_in[2];
    const float* eWhh   = (const float*)d_in[3];
    const float* eb     = (const float*)d_in[4];
    const float* elW    = (const float*)d_in[5];
    const float* elb    = (const float*)d_in[6];
    const float* dlW    = (const float*)d_in[7];
    const float* dlb    = (const float*)d_in[8];
    const float* dWih   = (const float*)d_in[9];
    const float* dWhh   = (const float*)d_in[10];
    const float* db     = (const float*)d_in[11];
    const float* outW   = (const float*)d_in[12];
    const float* outb   = (const float*)d_in[13];
    float* out = (float*)d_out;

    float* ws    = (float*)d_ws;
    float* h_enc = ws;
    float* c_enc = ws + (long)B * H;
    float* hd    = ws + 2L * B * H;
    float* y0c   = ws + 3L * B * H;
    float* acc2  = ws + 3L * B * H + B;

    float* out_pad = out + 1;
    float* out_y   = out + 1 + (long)B * T;
    float* out_hz  = out + 1 + 2L * (long)B * T;

    hipMemcpyAsync(out_pad, padded, (long)B * T * sizeof(float),
                   hipMemcpyDeviceToDevice, stream);
    hipMemsetAsync(acc2, 0, 2 * sizeof(float), stream);

    enc_kernel<<<NB, NTHREADS, 0, stream>>>(padded, seq, eWih, eWhh, eb, h_enc, c_enc);
    mid_kernel<<<B / 256, 256, 0, stream>>>(h_enc, elW, elb, dlW, dlb, outW, outb,
                                            out_hz, hd, y0c);
    dec_kernel<<<NB, NTHREADS, 0, stream>>>(hd, c_enc, dWih, dWhh, db, outW, outb, y0c, out_y);
    loss_kernel<<<1024, 256, 0, stream>>>(padded, out_y, seq, acc2);
    fin_kernel<<<1, 1, 0, stream>>>(acc2, out);
}

// Round 5
// 1806.206 us; speedup vs baseline: 1.3356x; 1.3356x over previous
//
#include <hip/hip_runtime.h>

#define B 4096
#define T 2048
#define H 64
#define NBATCH 16
#define NB (B / NBATCH)     // 256 blocks -> 1 per CU
#define NTHREADS 512        // 8 waves -> 2 waves/SIMD, 2 cells/lane (dual-tile)

typedef __attribute__((ext_vector_type(8))) short short8;
typedef __attribute__((ext_vector_type(4))) float f32x4;

__device__ __forceinline__ float ex2(float x) { return __builtin_amdgcn_exp2f(x); }
__device__ __forceinline__ unsigned short f2bf(float f) {  // RNE f32->bf16
    unsigned u = __builtin_bit_cast(unsigned, f);
    u += 0x7fffu + ((u >> 16) & 1u);
    return (unsigned short)(u >> 16);
}
// Pack two f32 -> two bf16 (RNE) in one instruction.
__device__ __forceinline__ unsigned pk_bf16(float a, float b) {
    unsigned r;
    asm("v_cvt_pk_bf16_f32 %0, %1, %2" : "=v"(r) : "v"(a), "v"(b));
    return r;
}
// LDS-only barrier: drain lgkm (ds ops) but leave global loads in flight.
__device__ __forceinline__ void lds_barrier() {
    asm volatile("s_waitcnt lgkmcnt(0)\n\ts_barrier" ::: "memory");
}

// Fused LSTM cell update. Exact math, one rcp per product:
//   sigm(a)*tanh(b) = (1-v) / ((1+p)(1+v)), p=2^(-1.4427a), v=2^(-2.8854b).
// Gate pre-activations are bounded (|a|<~11 given uniform(+-1/8) weights) so
// the 2^... terms never overflow; tanh(c) input clamped to +-15 (exact there).
// z = (i, f, g, o) gate pre-activations.
__device__ __forceinline__ void cellstep(const f32x4 z, float& cs, float& hs, bool act) {
    const float KE = -1.4426950408889634f;   // -1/ln2
    const float KT = -2.8853900817779268f;   // -2/ln2
    float pf = ex2(KE * z[1]);
    float f_ = __builtin_amdgcn_rcpf(1.0f + pf);              // sigm(f)
    float p0 = ex2(KE * z[0]);
    float v_ = ex2(KT * z[2]);
    float ig = (1.0f - v_) * __builtin_amdgcn_rcpf((1.0f + p0) * (1.0f + v_));
    float cn = __builtin_fmaf(f_, cs, ig);                    // c' = f*c + i*g
    float cc = fminf(15.0f, fmaxf(-15.0f, cn));
    float s_ = ex2(KE * z[3]);
    float r_ = ex2(KT * cc);
    float hn = (1.0f - r_) * __builtin_amdgcn_rcpf((1.0f + s_) * (1.0f + r_));
    if (act) { cs = cn; hs = hn; }                            // o*tanh(c')
}

// ---------------------------------------------------------------------------
// Encoder: 256 blocks x 512 threads (8 waves), 16 batches/block, 2 cells/lane.
// Wave w owns units w*8..w*8+7 as TWO 16-row MFMA tiles sharing one B-frag.
// A-row remap G(m,rt) = (m&3)*64 + w*8 + 2*(m>>2) + rt puts lane (lo,hi)'s
// two cells at ADJACENT units uA = w*8+2hi (tile 0), uB = uA+1 (tile 1):
// h-writeback = one pk_bf16 + one aligned ds_write_b32, conflict-free.
// ---------------------------------------------------------------------------
extern "C" __global__ void __launch_bounds__(NTHREADS, 2)
enc_kernel(const float* __restrict__ padded, const int* __restrict__ seq_len,
           const float* __restrict__ Wih, const float* __restrict__ Whh,
           const float* __restrict__ bias,
           float* __restrict__ h_out, float* __restrict__ c_out)
{
    __shared__ unsigned short hX[2][NBATCH][72];
    __shared__ int slen[NBATCH];

    const int tid = threadIdx.x;
    const int w = tid >> 6, L = tid & 63, lo = L & 15, hi = L >> 4;
    const int b0 = blockIdx.x * NBATCH;
    const int unitA = w * 8 + 2 * hi;      // tile 0 (even)
    const int unitB = unitA + 1;           // tile 1 (odd)

    // A-frags, remapped rows G(m,rt) = (m&3)*64 + w*8 + 2*(m>>2) + rt
    short8 af[2][2];
    #pragma unroll
    for (int rt = 0; rt < 2; ++rt) {
        const int G = (lo & 3) * 64 + w * 8 + 2 * (lo >> 2) + rt;
        #pragma unroll
        for (int kk = 0; kk < 2; ++kk) {
            const float* src = Whh + (long)G * H + kk * 32 + hi * 8;
            short8 f;
            #pragma unroll
            for (int j = 0; j < 8; ++j) f[j] = (short)f2bf(src[j]);
            af[rt][kk] = f;
        }
    }
    // C row hi*4+r of tile rt = gate r of unit w*8+2hi+rt, col = batch lo
    float b_g[2][4], wi_g[2][4];
    #pragma unroll
    for (int rt = 0; rt < 2; ++rt)
        #pragma unroll
        for (int r = 0; r < 4; ++r) {
            const int G2 = r * 64 + w * 8 + 2 * hi + rt;
            b_g[rt][r] = bias[G2];
            wi_g[rt][r] = Wih[G2];
        }

    for (int idx = tid; idx < NBATCH * 64; idx += NTHREADS)
        hX[0][idx >> 6][idx & 63] = 0;
    if (tid < NBATCH) slen[tid] = seq_len[b0 + tid];
    lds_barrier();

    int maxlen = 1;
    #pragma unroll
    for (int i = 0; i < NBATCH; ++i) maxlen = max(maxlen, slen[i]);
    const int len_lo = slen[lo];

    const float* xrow = padded + (long)(b0 + lo) * T;
    f32x4 xc = *(const f32x4*)(xrow);
    f32x4 xn = *(const f32x4*)(xrow + 4);

    float csA = 0.f, hsA = 0.f, csB = 0.f, hsB = 0.f;

#define ESTEP(P, XI)                                                          \
    {                                                                         \
        const float x = xc[XI];                                               \
        short8 hb0 = *(const short8*)&hX[P][lo][hi * 8];                      \
        short8 hb1 = *(const short8*)&hX[P][lo][32 + hi * 8];                 \
        f32x4 z0 = {b_g[0][0] + wi_g[0][0] * x, b_g[0][1] + wi_g[0][1] * x,   \
                    b_g[0][2] + wi_g[0][2] * x, b_g[0][3] + wi_g[0][3] * x};  \
        f32x4 z1 = {b_g[1][0] + wi_g[1][0] * x, b_g[1][1] + wi_g[1][1] * x,   \
                    b_g[1][2] + wi_g[1][2] * x, b_g[1][3] + wi_g[1][3] * x};  \
        z0 = __builtin_amdgcn_mfma_f32_16x16x32_bf16(af[0][0], hb0, z0, 0,0,0); \
        z1 = __builtin_amdgcn_mfma_f32_16x16x32_bf16(af[1][0], hb0, z1, 0,0,0); \
        z0 = __builtin_amdgcn_mfma_f32_16x16x32_bf16(af[0][1], hb1, z0, 0,0,0); \
        z1 = __builtin_amdgcn_mfma_f32_16x16x32_bf16(af[1][1], hb1, z1, 0,0,0); \
        const bool act = (t + XI) < len_lo;                                   \
        cellstep(z0, csA, hsA, act);                                          \
        cellstep(z1, csB, hsB, act);                                          \
        *(unsigned*)&hX[(P) ^ 1][lo][unitA] = pk_bf16(hsA, hsB);              \
        lds_barrier();                                                        \
    }

    for (int t = 0; t < maxlen; t += 4) {
        int nb = t + 8; if (nb > T - 4) nb = T - 4;
        f32x4 xf = *(const f32x4*)(xrow + nb);   // 8-step-ahead prefetch
        ESTEP(0, 0) ESTEP(1, 1) ESTEP(0, 2) ESTEP(1, 3)
        xc = xn; xn = xf;
    }
#undef ESTEP

    *(float2*)&h_out[(long)(b0 + lo) * H + unitA] = make_float2(hsA, hsB);
    *(float2*)&c_out[(long)(b0 + lo) * H + unitA] = make_float2(csA, csB);
}

// ---------------------------------------------------------------------------
// Bottleneck + y0 correction term for the decoder's rank-1 fold.
// ---------------------------------------------------------------------------
extern "C" __global__ void __launch_bounds__(256)
mid_kernel(const float* __restrict__ h_enc,
           const float* __restrict__ eW, const float* __restrict__ eb,
           const float* __restrict__ dW, const float* __restrict__ db,
           const float* __restrict__ outW, const float* __restrict__ outb,
           float* __restrict__ hz_out, float* __restrict__ hd_out,
           float* __restrict__ y0c)
{
    int b = blockIdx.x * blockDim.x + threadIdx.x;
    if (b >= B) return;
    const float* h = h_enc + (long)b * H;
    float hz[3];
    #pragma unroll
    for (int j = 0; j < 3; ++j) {
        float s = eb[j];
        for (int k = 0; k < H; ++k) s += h[k] * eW[j*H + k];
        hz[j] = 1.0f / (1.0f + __builtin_expf(-s));
        hz_out[b*3 + j] = hz[j];
    }
    float y0 = outb[0];
    for (int u = 0; u < H; ++u) {
        float hd = db[u] + hz[0]*dW[u*3] + hz[1]*dW[u*3+1] + hz[2]*dW[u*3+2];
        hd_out[(long)b*H + u] = hd;
        y0 += outW[u] * hd;
    }
    y0c[b] = y0;
}

// ---------------------------------------------------------------------------
// Decoder: rank-1 fold (W' = Whh + Wih (x) outW, b' = b + Wih*outb) -> pure
// LSTM. Same 16-batch / 8-wave / dual-tile / adjacent-unit structure as the
// encoder. y_{t-1} recovered via 2 extra MFMAs rotating across waves
// (w==t&7), one step delayed. t=0 correction peeled.
// ---------------------------------------------------------------------------
extern "C" __global__ void __launch_bounds__(NTHREADS, 2)
dec_kernel(const float* __restrict__ hd, const float* __restrict__ c_in,
           const float* __restrict__ Wih, const float* __restrict__ Whh,
           const float* __restrict__ bias, const float* __restrict__ outW,
           const float* __restrict__ outb, const float* __restrict__ y0c,
           float* __restrict__ y_out)
{
    __shared__ unsigned short hX[2][NBATCH][72];

    const int tid = threadIdx.x;
    const int w = tid >> 6, L = tid & 63, lo = L & 15, hi = L >> 4;
    const int b0 = blockIdx.x * NBATCH;
    const int unitA = w * 8 + 2 * hi;
    const int unitB = unitA + 1;

    short8 af[2][2];
    #pragma unroll
    for (int rt = 0; rt < 2; ++rt) {
        const int G = (lo & 3) * 64 + w * 8 + 2 * (lo >> 2) + rt;
        const float wir = Wih[G];
        #pragma unroll
        for (int kk = 0; kk < 2; ++kk) {
            const float* src = Whh + (long)G * H + kk * 32 + hi * 8;
            const float* ow  = outW + kk * 32 + hi * 8;
            short8 f;
            #pragma unroll
            for (int j = 0; j < 8; ++j) f[j] = (short)f2bf(src[j] + wir * ow[j]);
            af[rt][kk] = f;
        }
    }
    const float outb_s = outb[0];
    const float y0 = y0c[b0 + lo];
    float zb[2][4], corr[2][4];
    #pragma unroll
    for (int rt = 0; rt < 2; ++rt)
        #pragma unroll
        for (int r = 0; r < 4; ++r) {
            const int G2 = r * 64 + w * 8 + 2 * hi + rt;
            zb[rt][r] = bias[G2] + Wih[G2] * outb_s;
            corr[rt][r] = Wih[G2] * y0;
        }

    short8 ya[2];   // y-extraction A-frag: row 0 = outW, rows 1..15 = 0
    #pragma unroll
    for (int kk = 0; kk < 2; ++kk) {
        short8 f = (short8)0;
        if (lo == 0)
            #pragma unroll
            for (int j = 0; j < 8; ++j) f[j] = (short)f2bf(outW[kk*32 + hi*8 + j]);
        ya[kk] = f;
    }

    for (int idx = tid; idx < NBATCH * 64; idx += NTHREADS)
        hX[0][idx >> 6][idx & 63] = f2bf(hd[(long)(b0 + (idx >> 6)) * H + (idx & 63)]);
    float2 c2 = *(const float2*)&c_in[(long)(b0 + lo) * H + unitA];
    float csA = c2.x, csB = c2.y, hsA = 0.f, hsB = 0.f;
    lds_barrier();

#define DSTEP(P, CORR, TT)                                                    \
    {                                                                         \
        short8 hb0 = *(const short8*)&hX[P][lo][hi * 8];                      \
        short8 hb1 = *(const short8*)&hX[P][lo][32 + hi * 8];                 \
        f32x4 z0 = {zb[0][0], zb[0][1], zb[0][2], zb[0][3]};                  \
        f32x4 z1 = {zb[1][0], zb[1][1], zb[1][2], zb[1][3]};                  \
        z0 = __builtin_amdgcn_mfma_f32_16x16x32_bf16(af[0][0], hb0, z0, 0,0,0); \
        z1 = __builtin_amdgcn_mfma_f32_16x16x32_bf16(af[1][0], hb0, z1, 0,0,0); \
        z0 = __builtin_amdgcn_mfma_f32_16x16x32_bf16(af[0][1], hb1, z0, 0,0,0); \
        z1 = __builtin_amdgcn_mfma_f32_16x16x32_bf16(af[1][1], hb1, z1, 0,0,0); \
        if (w == ((TT) & 7)) {  /* y_{t-1} = outW.h_{t-1}+outb, rotated */    \
            f32x4 zy = {outb_s, outb_s, outb_s, outb_s};                      \
            zy = __builtin_amdgcn_mfma_f32_16x16x32_bf16(ya[0], hb0, zy, 0,0,0); \
            zy = __builtin_amdgcn_mfma_f32_16x16x32_bf16(ya[1], hb1, zy, 0,0,0); \
            if ((TT) > 0 && hi == 0)                                          \
                y_out[(long)(b0 + lo) * T + ((TT) - 1)] = zy[0];              \
        }                                                                     \
        if (CORR) {                                                           \
            _Pragma("unroll")                                                 \
            for (int r = 0; r < 4; ++r) { z0[r] -= corr[0][r]; z1[r] -= corr[1][r]; } \
        }                                                                     \
        cellstep(z0, csA, hsA, true);                                         \
        cellstep(z1, csB, hsB, true);                                         \
        *(unsigned*)&hX[(P) ^ 1][lo][unitA] = pk_bf16(hsA, hsB);              \
        lds_barrier();                                                        \
    }

    DSTEP(0, 1, 0) DSTEP(1, 0, 1) DSTEP(0, 0, 2) DSTEP(1, 0, 3)
    for (int t = 4; t < T; t += 4) {
        DSTEP(0, 0, t) DSTEP(1, 0, t + 1) DSTEP(0, 0, t + 2) DSTEP(1, 0, t + 3)
    }
#undef DSTEP

    if (w == 0) {       // final y_{T-1} (T even -> parity 0)
        short8 hb0 = *(const short8*)&hX[0][lo][hi * 8];
        short8 hb1 = *(const short8*)&hX[0][lo][32 + hi * 8];
        f32x4 zy = {outb_s, outb_s, outb_s, outb_s};
        zy = __builtin_amdgcn_mfma_f32_16x16x32_bf16(ya[0], hb0, zy, 0,0,0);
        zy = __builtin_amdgcn_mfma_f32_16x16x32_bf16(ya[1], hb1, zy, 0,0,0);
        if (hi == 0) y_out[(long)(b0 + lo) * T + (T - 1)] = zy[0];
    }
}

// ---------------------------------------------------------------------------
extern "C" __global__ void __launch_bounds__(256)
loss_kernel(const float* __restrict__ padded, const float* __restrict__ y,
            const int* __restrict__ seq_len, float* __restrict__ acc2)
{
    const long n4 = (long)B * T / 4;
    long i0 = (long)(blockIdx.x * blockDim.x + threadIdx.x);
    long stride = (long)gridDim.x * blockDim.x;
    float s = 0.f, cnt = 0.f;
    for (long i = i0; i < n4; i += stride) {
        int b = (int)(i >> 9);                  // T/4 = 512
        int t = (int)(i & 511) * 4;
        int len = seq_len[b];
        f32x4 pv = *(const f32x4*)&padded[i * 4];
        f32x4 yv = *(const f32x4*)&y[i * 4];
        #pragma unroll
        for (int e = 0; e < 4; ++e)
            if (t + e < len) { float d = pv[e] - yv[e]; s += d * d; cnt += 1.0f; }
    }
    for (int m = 1; m < 64; m <<= 1) { s += __shfl_xor(s, m); cnt += __shfl_xor(cnt, m); }
    if ((threadIdx.x & 63) == 0) { atomicAdd(&acc2[0], s); atomicAdd(&acc2[1], cnt); }
}

extern "C" __global__ void fin_kernel(const float* __restrict__ acc2, float* __restrict__ out)
{
    out[0] = acc2[0] / acc2[1];
}

// ---------------------------------------------------------------------------
extern "C" void kernel_launch(void* const* d_in, const int* in_sizes, int n_in,
                              void* d_out, int out_size, void* d_ws, size_t ws_size,
                              hipStream_t stream)
{
    const float* padded = (const float*)d_in[0];
    const int*   seq    = (const int*)  d_in[1];
    const float* eWih   = (const float*)d_in[2];
    const float* eWhh   = (const float*)d_in[3];
    const float* eb     = (const float*)d_in[4];
    const float* elW    = (const float*)d_in[5];
    const float* elb    = (const float*)d_in[6];
    const float* dlW    = (const float*)d_in[7];
    const float* dlb    = (const float*)d_in[8];
    const float* dWih   = (const float*)d_in[9];
    const float* dWhh   = (const float*)d_in[10];
    const float* db     = (const float*)d_in[11];
    const float* outW   = (const float*)d_in[12];
    const float* outb   = (const float*)d_in[13];
    float* out = (float*)d_out;

    float* ws    = (float*)d_ws;
    float* h_enc = ws;
    float* c_enc = ws + (long)B * H;
    float* hd    = ws + 2L * B * H;
    float* y0c   = ws + 3L * B * H;
    float* acc2  = ws + 3L * B * H + B;

    float* out_pad = out + 1;
    float* out_y   = out + 1 + (long)B * T;
    float* out_hz  = out + 1 + 2L * (long)B * T;

    hipMemcpyAsync(out_pad, padded, (long)B * T * sizeof(float),
                   hipMemcpyDeviceToDevice, stream);
    hipMemsetAsync(acc2, 0, 2 * sizeof(float), stream);

    enc_kernel<<<NB, NTHREADS, 0, stream>>>(padded, seq, eWih, eWhh, eb, h_enc, c_enc);
    mid_kernel<<<B / 256, 256, 0, stream>>>(h_enc, elW, elb, dlW, dlb, outW, outb,
                                            out_hz, hd, y0c);
    dec_kernel<<<NB, NTHREADS, 0, stream>>>(hd, c_enc, dWih, dWhh, db, outW, outb, y0c, out_y);
    loss_kernel<<<1024, 256, 0, stream>>>(padded, out_y, seq, acc2);
    fin_kernel<<<1, 1, 0, stream>>>(acc2, out);
}